// Round 2
// baseline (398.484 us; speedup 1.0000x reference)
//
#include <hip/hip_runtime.h>
#include <hip/hip_bf16.h>
#include <stdint.h>

// Problem dims (fixed by reference)
#define BB 4
#define SS 2048
#define EE 512
#define HH 1024
// token rows = 8192, ext rows = 2048

typedef unsigned short u16;
typedef __attribute__((ext_vector_type(8))) short bf16x8;
typedef __attribute__((ext_vector_type(4))) float f32x4;

__device__ __forceinline__ u16 f2bf(float f) {
  union { float f; unsigned u; } v; v.f = f;
  unsigned r = v.u + 0x7fffu + ((v.u >> 16) & 1u);
  return (u16)(r >> 16);
}
__device__ __forceinline__ float bf2f(u16 h) {
  union { unsigned u; float f; } v; v.u = ((unsigned)h) << 16;
  return v.f;
}
__device__ __forceinline__ void async16(void* lds, const void* g) {
  __builtin_amdgcn_global_load_lds(
      (const __attribute__((address_space(1))) unsigned int*)g,
      (__attribute__((address_space(3))) unsigned int*)lds, 16, 0, 0);
}

// ---------------------------------------------------------------------------
// Core 128x128 BT-GEMM: C = A * B^T, A[M][K] row-major, B[N][K] row-major.
// Both operands optionally split (hi+lo bf16): acc += Ah*Bh + Ah*Bl + Al*Bh.
// 256 threads = 4 waves; wave w computes 64x64 at (w>>1, w&1).
// LDS layout XOR-swizzled: row r's 16B k-chunk c lives at position
// c ^ ((r>>1)&3). This makes the 8 lanes of each ds_read_b128 phase-group
// hit 8 distinct 16B slots (conflict-free) instead of 2 (4-way conflict).
// Staging stays global_load_lds-legal: only the global SOURCE column is
// permuted per lane; LDS dest remains base + lane*16.
// ---------------------------------------------------------------------------
template <bool SPLIT>
__device__ __forceinline__ void gemm_core(
    const u16* Ah, const u16* Al, const u16* Bh, const u16* Bl, int K,
    u16* lAh, u16* lAl, u16* lBh, u16* lBl, f32x4 acc[4][4]) {
  const int tid = threadIdx.x;
  const int wave = tid >> 6;
  const int lane = tid & 63;
  const int lrow = lane >> 2;  // 0..15 within the 16-row staging group
  // swizzled source chunk: (lane&3) ^ ((row_within_group>>1)&3)
  const int lcol = (((lane & 3) ^ ((lane >> 3) & 3))) * 8;
  const int waveM = (wave >> 1) * 64;
  const int waveN = (wave & 1) * 64;
  const int frow = lane & 15;
  // fragment read: chunk (lane>>4) lives at position (lane>>4) ^ ((frow>>1)&3)
  const int fk = ((lane >> 4) ^ ((frow >> 1) & 3)) * 8;

  for (int k0 = 0; k0 < K; k0 += 32) {
    __syncthreads();  // previous iteration's LDS reads done
#pragma unroll
    for (int i = 0; i < 2; ++i) {
      const int r0 = (wave * 2 + i) * 16;  // rows r0..r0+15 of the tile
      const size_t goff = (size_t)(r0 + lrow) * K + (k0 + lcol);
      async16(&lAh[r0 * 32], Ah + goff);
      async16(&lBh[r0 * 32], Bh + goff);
      if (SPLIT) {
        async16(&lAl[r0 * 32], Al + goff);
        async16(&lBl[r0 * 32], Bl + goff);
      }
    }
    __syncthreads();  // staging complete (barrier drains vmcnt)

    bf16x8 ah[4], bh[4], al[4], bl[4];
#pragma unroll
    for (int i = 0; i < 4; ++i) {
      ah[i] = *(const bf16x8*)&lAh[(waveM + i * 16 + frow) * 32 + fk];
      bh[i] = *(const bf16x8*)&lBh[(waveN + i * 16 + frow) * 32 + fk];
      if (SPLIT) {
        al[i] = *(const bf16x8*)&lAl[(waveM + i * 16 + frow) * 32 + fk];
        bl[i] = *(const bf16x8*)&lBl[(waveN + i * 16 + frow) * 32 + fk];
      }
    }
#pragma unroll
    for (int i = 0; i < 4; ++i)
#pragma unroll
      for (int j = 0; j < 4; ++j) {
        acc[i][j] = __builtin_amdgcn_mfma_f32_16x16x32_bf16(ah[i], bh[j], acc[i][j], 0, 0, 0);
        if (SPLIT) {
          acc[i][j] = __builtin_amdgcn_mfma_f32_16x16x32_bf16(ah[i], bl[j], acc[i][j], 0, 0, 0);
          acc[i][j] = __builtin_amdgcn_mfma_f32_16x16x32_bf16(al[i], bh[j], acc[i][j], 0, 0, 0);
        }
      }
  }
}

// ---------------------------------------------------------------------------
// Elementwise: fp32 -> (hi, lo) bf16 split
// ---------------------------------------------------------------------------
__global__ __launch_bounds__(256) void split_kernel(const float* __restrict__ x,
                                                    u16* __restrict__ hi,
                                                    u16* __restrict__ lo, int n4) {
  const int i = blockIdx.x * 256 + threadIdx.x;
  if (i >= n4) return;
  const float4 v = ((const float4*)x)[i];
  ushort4 h, l;
  h.x = f2bf(v.x); l.x = f2bf(v.x - bf2f(h.x));
  h.y = f2bf(v.y); l.y = f2bf(v.y - bf2f(h.y));
  h.z = f2bf(v.z); l.z = f2bf(v.z - bf2f(h.z));
  h.w = f2bf(v.w); l.w = f2bf(v.w - bf2f(h.w));
  ((ushort4*)hi)[i] = h;
  ((ushort4*)lo)[i] = l;
}

// Transpose-split W: Wt[n'][k] = W_{n'>>10}[k][n'&1023], n' in [0,3072)
__global__ void wsplit_kernel(const float* __restrict__ Wq, const float* __restrict__ Wk,
                              const float* __restrict__ Wv, u16* __restrict__ wt_hi,
                              u16* __restrict__ wt_lo) {
  __shared__ float tile[32][33];
  const int k0 = blockIdx.x * 32;
  const int n0g = blockIdx.y * 32;
  const int which = n0g >> 10;
  const float* W = which == 0 ? Wq : (which == 1 ? Wk : Wv);
  const int n0 = n0g & 1023;
  const int tx = threadIdx.x, ty = threadIdx.y;
#pragma unroll
  for (int i = 0; i < 32; i += 8)
    tile[ty + i][tx] = W[(size_t)(k0 + ty + i) * 1024 + n0 + tx];
  __syncthreads();
#pragma unroll
  for (int i = 0; i < 32; i += 8) {
    const int np = n0g + ty + i;
    const float v = tile[tx][ty + i];
    const size_t idx = (size_t)np * 1024 + k0 + tx;
    const u16 h = f2bf(v);
    wt_hi[idx] = h;
    wt_lo[idx] = f2bf(v - bf2f(h));
  }
}

// ---------------------------------------------------------------------------
// Projection GEMM: rows = [8192 token rows | 2048 ext rows], cols = [q|k|v]
// q/k col-tiles (ntile<16): split path. v col-tiles: plain bf16 path.
// ext-row blocks skip q col-tiles entirely.
// ---------------------------------------------------------------------------
__global__ __launch_bounds__(256, 4) void proj_kernel(
    const u16* __restrict__ xh_hi, const u16* __restrict__ xh_lo,
    const u16* __restrict__ xe_hi, const u16* __restrict__ xe_lo,
    const u16* __restrict__ wt_hi, const u16* __restrict__ wt_lo,
    const float* __restrict__ bq, const float* __restrict__ bk,
    const float* __restrict__ bv, u16* __restrict__ q_hi, u16* __restrict__ q_lo,
    u16* __restrict__ kt_hi, u16* __restrict__ kt_lo, u16* __restrict__ vt,
    u16* __restrict__ ke_hi, u16* __restrict__ ke_lo, u16* __restrict__ veT) {
  const int ntile = blockIdx.x;  // 0..23 (3072 cols)
  const int mtile = blockIdx.y;  // 0..79 (10240 rows)
  const bool extRows = (mtile >= 64);
  if (extRows && ntile < 8) return;  // ext rows need no q

  __shared__ u16 lds[4][128 * 32];

  const u16* Ah;
  const u16* Al;
  int rowA;
  if (!extRows) { Ah = xh_hi; Al = xh_lo; rowA = mtile * 128; }
  else          { Ah = xe_hi; Al = xe_lo; rowA = (mtile - 64) * 128; }
  const int rowB = ntile * 128;

  f32x4 acc[4][4];
#pragma unroll
  for (int i = 0; i < 4; ++i)
#pragma unroll
    for (int j = 0; j < 4; ++j)
#pragma unroll
      for (int r = 0; r < 4; ++r) acc[i][j][r] = 0.0f;

  if (ntile < 16)
    gemm_core<true>(Ah + (size_t)rowA * HH, Al + (size_t)rowA * HH,
                    wt_hi + (size_t)rowB * HH, wt_lo + (size_t)rowB * HH, HH,
                    lds[0], lds[1], lds[2], lds[3], acc);
  else
    gemm_core<false>(Ah + (size_t)rowA * HH, nullptr,
                     wt_hi + (size_t)rowB * HH, nullptr, HH,
                     lds[0], lds[1], lds[2], lds[3], acc);

  const int tid = threadIdx.x, wave = tid >> 6, lane = tid & 63;
  const int waveM = (wave >> 1) * 64, waveN = (wave & 1) * 64;
  const int colIn16 = lane & 15, rowQuad = (lane >> 4) * 4;

#pragma unroll
  for (int j = 0; j < 4; ++j) {
    const int c = ntile * 128 + waveN + j * 16 + colIn16;  // 0..3071
    float bias;
    if (c < 1024) bias = bq[c];
    else if (c < 2048) bias = bk[c - 1024];
    else bias = bv[c - 2048];
#pragma unroll
    for (int i = 0; i < 4; ++i) {
#pragma unroll
      for (int r = 0; r < 4; ++r) {
        const int lrowIdx = waveM + i * 16 + rowQuad + r;  // 0..127
        const float val = acc[i][j][r] + bias;
        if (c < 1024) {  // q (token rows only)
          const size_t idx = (size_t)(mtile * 128 + lrowIdx) * HH + c;
          const u16 h = f2bf(val);
          q_hi[idx] = h;
          q_lo[idx] = f2bf(val - bf2f(h));
        } else if (c < 2048) {  // k
          const int c2 = c - 1024;
          if (!extRows) {
            const size_t idx = (size_t)(mtile * 128 + lrowIdx) * HH + c2;
            const u16 h = f2bf(val);
            kt_hi[idx] = h;
            kt_lo[idx] = f2bf(val - bf2f(h));
          } else {
            const int ge = (mtile - 64) * 128 + lrowIdx;
            const size_t idx = (size_t)ge * HH + c2;
            const u16 h = f2bf(val);
            ke_hi[idx] = h;
            ke_lo[idx] = f2bf(val - bf2f(h));
          }
        } else {  // v
          const int c2 = c - 2048;
          if (!extRows) {
            vt[(size_t)(mtile * 128 + lrowIdx) * HH + c2] = f2bf(val);
          } else {
            const int ge = (mtile - 64) * 128 + lrowIdx;  // 0..2047
            const int bb = ge >> 9, e = ge & 511;
            veT[(size_t)(bb * HH + c2) * EE + e] = f2bf(val);  // [B][H][E]
          }
        }
      }
    }
  }
}

// s_self[t] = q[t] . k_tok[t]  (fp32 via hi+lo reconstruction)
__global__ __launch_bounds__(256) void selfdot_kernel(
    const u16* __restrict__ q_hi, const u16* __restrict__ q_lo,
    const u16* __restrict__ kt_hi, const u16* __restrict__ kt_lo,
    float* __restrict__ s_self) {
  const int t = blockIdx.x * 4 + (threadIdx.x >> 6);
  const int lane = threadIdx.x & 63;
  const size_t base = (size_t)t * HH;
  float acc = 0.f;
#pragma unroll
  for (int it = 0; it < 4; ++it) {
    const int off = it * 256 + lane * 4;
    const ushort4 qh = *(const ushort4*)&q_hi[base + off];
    const ushort4 ql = *(const ushort4*)&q_lo[base + off];
    const ushort4 kh = *(const ushort4*)&kt_hi[base + off];
    const ushort4 kl = *(const ushort4*)&kt_lo[base + off];
    acc += (bf2f(qh.x) + bf2f(ql.x)) * (bf2f(kh.x) + bf2f(kl.x));
    acc += (bf2f(qh.y) + bf2f(ql.y)) * (bf2f(kh.y) + bf2f(kl.y));
    acc += (bf2f(qh.z) + bf2f(ql.z)) * (bf2f(kh.z) + bf2f(kl.z));
    acc += (bf2f(qh.w) + bf2f(ql.w)) * (bf2f(kh.w) + bf2f(kl.w));
  }
#pragma unroll
  for (int m = 32; m > 0; m >>= 1) acc += __shfl_xor(acc, m, 64);
  if (lane == 0) s_self[t] = acc;
}

// Score GEMM per batch: s_ext[b][s][e] = q[b,s,:] . k_ext[b,e,:]  (split)
__global__ __launch_bounds__(256, 4) void score_kernel(
    const u16* __restrict__ q_hi, const u16* __restrict__ q_lo,
    const u16* __restrict__ ke_hi, const u16* __restrict__ ke_lo,
    float* __restrict__ s_ext) {
  const int b = blockIdx.z;
  const int mtile = blockIdx.y;  // 0..15
  const int ntile = blockIdx.x;  // 0..3
  __shared__ u16 lds[4][128 * 32];
  const size_t aoff = ((size_t)b * SS + mtile * 128) * HH;
  const size_t boff = ((size_t)b * EE + ntile * 128) * HH;

  f32x4 acc[4][4];
#pragma unroll
  for (int i = 0; i < 4; ++i)
#pragma unroll
    for (int j = 0; j < 4; ++j)
#pragma unroll
      for (int r = 0; r < 4; ++r) acc[i][j][r] = 0.0f;

  gemm_core<true>(q_hi + aoff, q_lo + aoff, ke_hi + boff, ke_lo + boff, HH,
                  lds[0], lds[1], lds[2], lds[3], acc);

  const int tid = threadIdx.x, wave = tid >> 6, lane = tid & 63;
  const int waveM = (wave >> 1) * 64, waveN = (wave & 1) * 64;
  const int colIn16 = lane & 15, rowQuad = (lane >> 4) * 4;
#pragma unroll
  for (int j = 0; j < 4; ++j) {
    const int e = ntile * 128 + waveN + j * 16 + colIn16;
#pragma unroll
    for (int i = 0; i < 4; ++i)
#pragma unroll
      for (int r = 0; r < 4; ++r) {
        const int s = mtile * 128 + waveM + i * 16 + rowQuad + r;
        s_ext[((size_t)b * SS + s) * EE + e] = acc[i][j][r];
      }
  }
}

// Softmax over [s_self, s_ext[0..511]]; probs -> bf16, p_self -> fp32
__global__ __launch_bounds__(256) void softmax_kernel(
    const float* __restrict__ s_self, const float* __restrict__ s_ext,
    u16* __restrict__ probs, float* __restrict__ p_self) {
  const int t = blockIdx.x * 4 + (threadIdx.x >> 6);
  const int lane = threadIdx.x & 63;
  const float* row = s_ext + (size_t)t * EE;
  const float4 v0 = *(const float4*)&row[lane * 4];
  const float4 v1 = *(const float4*)&row[256 + lane * 4];
  const float ss = s_self[t];
  float m = fmaxf(fmaxf(fmaxf(v0.x, v0.y), fmaxf(v0.z, v0.w)),
                  fmaxf(fmaxf(v1.x, v1.y), fmaxf(v1.z, v1.w)));
#pragma unroll
  for (int sh = 32; sh > 0; sh >>= 1) m = fmaxf(m, __shfl_xor(m, sh, 64));
  m = fmaxf(m, ss);
  const float e0 = __expf(v0.x - m), e1 = __expf(v0.y - m);
  const float e2 = __expf(v0.z - m), e3 = __expf(v0.w - m);
  const float e4 = __expf(v1.x - m), e5 = __expf(v1.y - m);
  const float e6 = __expf(v1.z - m), e7 = __expf(v1.w - m);
  float sum = ((e0 + e1) + (e2 + e3)) + ((e4 + e5) + (e6 + e7));
#pragma unroll
  for (int sh = 32; sh > 0; sh >>= 1) sum += __shfl_xor(sum, sh, 64);
  const float es = __expf(ss - m);
  const float inv = 1.0f / (sum + es);
  ushort4 p0, p1;
  p0.x = f2bf(e0 * inv); p0.y = f2bf(e1 * inv);
  p0.z = f2bf(e2 * inv); p0.w = f2bf(e3 * inv);
  p1.x = f2bf(e4 * inv); p1.y = f2bf(e5 * inv);
  p1.z = f2bf(e6 * inv); p1.w = f2bf(e7 * inv);
  *(ushort4*)&probs[(size_t)t * EE + lane * 4] = p0;
  *(ushort4*)&probs[(size_t)t * EE + 256 + lane * 4] = p1;
  if (lane == 0) p_self[t] = es * inv;
}

// PV GEMM per batch: out[b,s,h] = probs[b,s,:] . v_ext[b,:,h] + p_self*v_tok
// Plain path -> only 2 LDS buffers (16 KB) for better occupancy.
__global__ __launch_bounds__(256, 4) void pv_kernel(
    const u16* __restrict__ probs, const u16* __restrict__ veT,
    const float* __restrict__ p_self, const u16* __restrict__ vt,
    float* __restrict__ out) {
  const int b = blockIdx.z;
  const int mtile = blockIdx.y;  // 0..15 (S)
  const int ntile = blockIdx.x;  // 0..7  (H)
  __shared__ u16 lds[2][128 * 32];
  const size_t aoff = ((size_t)b * SS + mtile * 128) * EE;
  const size_t boff = ((size_t)b * HH + ntile * 128) * EE;

  f32x4 acc[4][4];
#pragma unroll
  for (int i = 0; i < 4; ++i)
#pragma unroll
    for (int j = 0; j < 4; ++j)
#pragma unroll
      for (int r = 0; r < 4; ++r) acc[i][j][r] = 0.0f;

  gemm_core<false>(probs + aoff, nullptr, veT + boff, nullptr, EE,
                   lds[0], nullptr, lds[1], nullptr, acc);

  const int tid = threadIdx.x, wave = tid >> 6, lane = tid & 63;
  const int waveM = (wave >> 1) * 64, waveN = (wave & 1) * 64;
  const int colIn16 = lane & 15, rowQuad = (lane >> 4) * 4;
#pragma unroll
  for (int j = 0; j < 4; ++j) {
    const int h = ntile * 128 + waveN + j * 16 + colIn16;
#pragma unroll
    for (int i = 0; i < 4; ++i)
#pragma unroll
      for (int r = 0; r < 4; ++r) {
        const int s = mtile * 128 + waveM + i * 16 + rowQuad + r;
        const size_t t = (size_t)b * SS + s;
        out[t * HH + h] = acc[i][j][r] + p_self[t] * bf2f(vt[t * HH + h]);
      }
  }
}

extern "C" void kernel_launch(void* const* d_in, const int* in_sizes, int n_in,
                              void* d_out, int out_size, void* d_ws, size_t ws_size,
                              hipStream_t stream) {
  const float* hidden = (const float*)d_in[0];
  const float* ext    = (const float*)d_in[1];
  const float* Wq = (const float*)d_in[2];
  const float* bq = (const float*)d_in[3];
  const float* Wk = (const float*)d_in[4];
  const float* bk = (const float*)d_in[5];
  const float* Wv = (const float*)d_in[6];
  const float* bv = (const float*)d_in[7];
  float* out = (float*)d_out;

  char* ws = (char*)d_ws;
  size_t off = 0;
  auto alloc = [&](size_t bytes) {
    char* p = ws + off;
    off += (bytes + 255) & ~(size_t)255;
    return p;
  };
  const size_t TOK = 8192, EXT = 2048;
  u16* xh_hi = (u16*)alloc(TOK * HH * 2);
  u16* xh_lo = (u16*)alloc(TOK * HH * 2);
  u16* xe_hi = (u16*)alloc(EXT * HH * 2);
  u16* xe_lo = (u16*)alloc(EXT * HH * 2);
  u16* wt_hi = (u16*)alloc(3072ull * HH * 2);
  u16* wt_lo = (u16*)alloc(3072ull * HH * 2);
  u16* q_hi  = (u16*)alloc(TOK * HH * 2);
  u16* q_lo  = (u16*)alloc(TOK * HH * 2);
  u16* kt_hi = (u16*)alloc(TOK * HH * 2);
  u16* kt_lo = (u16*)alloc(TOK * HH * 2);
  u16* vt    = (u16*)alloc(TOK * HH * 2);
  u16* ke_hi = (u16*)alloc(EXT * HH * 2);
  u16* ke_lo = (u16*)alloc(EXT * HH * 2);
  u16* veT   = (u16*)alloc((size_t)BB * HH * EE * 2);
  float* s_self = (float*)alloc(TOK * 4);
  float* p_self = (float*)alloc(TOK * 4);
  float* s_ext  = (float*)alloc((size_t)BB * SS * EE * 4);
  u16* probs    = (u16*)alloc((size_t)BB * SS * EE * 2);

  // 1. split inputs to hi/lo bf16
  split_kernel<<<8192, 256, 0, stream>>>(hidden, xh_hi, xh_lo, (int)(TOK * HH / 4));
  split_kernel<<<2048, 256, 0, stream>>>(ext, xe_hi, xe_lo, (int)(EXT * HH / 4));
  wsplit_kernel<<<dim3(32, 96), dim3(32, 8), 0, stream>>>(Wq, Wk, Wv, wt_hi, wt_lo);

  // 2. fused projection GEMM (q,k split; v plain)
  proj_kernel<<<dim3(24, 80), 256, 0, stream>>>(
      xh_hi, xh_lo, xe_hi, xe_lo, wt_hi, wt_lo, bq, bk, bv,
      q_hi, q_lo, kt_hi, kt_lo, vt, ke_hi, ke_lo, veT);

  // 3. attention
  selfdot_kernel<<<2048, 256, 0, stream>>>(q_hi, q_lo, kt_hi, kt_lo, s_self);
  score_kernel<<<dim3(4, 16, 4), 256, 0, stream>>>(q_hi, q_lo, ke_hi, ke_lo, s_ext);
  softmax_kernel<<<2048, 256, 0, stream>>>(s_self, s_ext, probs, p_self);
  pv_kernel<<<dim3(8, 16, 4), 256, 0, stream>>>(probs, veT, p_self, vt, out);
}

// Round 3
// 375.273 us; speedup vs baseline: 1.0619x; 1.0619x over previous
//
#include <hip/hip_runtime.h>
#include <stdint.h>

// Problem dims (fixed by reference)
#define BB 4
#define SS 2048
#define EE 512
#define HH 1024
// token rows = 8192, ext rows = 2048

typedef _Float16 f16;
typedef __attribute__((ext_vector_type(8))) _Float16 f16x8;
typedef __attribute__((ext_vector_type(4))) _Float16 f16x4;
typedef __attribute__((ext_vector_type(4))) float f32x4;

__device__ __forceinline__ void async16(void* lds, const void* g) {
  __builtin_amdgcn_global_load_lds(
      (const __attribute__((address_space(1))) unsigned int*)g,
      (__attribute__((address_space(3))) unsigned int*)lds, 16, 0, 0);
}

// ---------------------------------------------------------------------------
// Core 128x128 BT-GEMM: C = A * B^T, A[M][K] fp16 row-major (hi only),
// B[N][K] fp16 row-major. SPLIT: B has hi+lo planes; acc += A*Bh + A*Bl
// (2-term fp16 split — dropped Al*B term is ~1e-4 relative, see header note).
// 256 threads = 4 waves; wave w computes 64x64 at (w>>1, w&1).
// LDS XOR-swizzle: row r's 16B k-chunk c stored at c ^ ((r>>1)&3) ->
// conflict-free ds_read_b128 (verified R2: SQ_LDS_BANK_CONFLICT 1.2e7 -> 0).
// ld = row stride (elements); K = contraction length for this block.
// ---------------------------------------------------------------------------
template <bool SPLIT>
__device__ __forceinline__ void gemm_core(
    const f16* A, const f16* Bh, const f16* Bl, int K, int ld,
    f16* lA, f16* lBh, f16* lBl, f32x4 acc[4][4]) {
  const int tid = threadIdx.x;
  const int wave = tid >> 6;
  const int lane = tid & 63;
  const int lrow = lane >> 2;  // 0..15 within 16-row staging group
  const int lcol = (((lane & 3) ^ ((lane >> 3) & 3))) * 8;  // swizzled source chunk
  const int waveM = (wave >> 1) * 64;
  const int waveN = (wave & 1) * 64;
  const int frow = lane & 15;
  const int fk = ((lane >> 4) ^ ((frow >> 1) & 3)) * 8;  // swizzled fragment pos

  for (int k0 = 0; k0 < K; k0 += 32) {
    __syncthreads();  // previous iteration's LDS reads done
#pragma unroll
    for (int i = 0; i < 2; ++i) {
      const int r0 = (wave * 2 + i) * 16;
      const size_t goff = (size_t)(r0 + lrow) * ld + (k0 + lcol);
      async16(&lA[r0 * 32], A + goff);
      async16(&lBh[r0 * 32], Bh + goff);
      if (SPLIT) async16(&lBl[r0 * 32], Bl + goff);
    }
    __syncthreads();  // staging complete

    f16x8 a[4], bh[4], bl[4];
#pragma unroll
    for (int i = 0; i < 4; ++i) {
      a[i] = *(const f16x8*)&lA[(waveM + i * 16 + frow) * 32 + fk];
      bh[i] = *(const f16x8*)&lBh[(waveN + i * 16 + frow) * 32 + fk];
      if (SPLIT) bl[i] = *(const f16x8*)&lBl[(waveN + i * 16 + frow) * 32 + fk];
    }
#pragma unroll
    for (int i = 0; i < 4; ++i)
#pragma unroll
      for (int j = 0; j < 4; ++j) {
        acc[i][j] = __builtin_amdgcn_mfma_f32_16x16x32_f16(a[i], bh[j], acc[i][j], 0, 0, 0);
        if (SPLIT)
          acc[i][j] = __builtin_amdgcn_mfma_f32_16x16x32_f16(a[i], bl[j], acc[i][j], 0, 0, 0);
      }
  }
}

// fp32 -> fp16 cast (A-side operands need no lo plane)
__global__ __launch_bounds__(256) void cast_kernel(const float* __restrict__ x,
                                                   f16* __restrict__ h, int n4) {
  const int i = blockIdx.x * 256 + threadIdx.x;
  if (i >= n4) return;
  const float4 v = ((const float4*)x)[i];
  f16x4 o;
  o.x = (f16)v.x; o.y = (f16)v.y; o.z = (f16)v.z; o.w = (f16)v.w;
  ((f16x4*)h)[i] = o;
}

// Transpose-split W: Wt[n'][k] = W_{n'>>10}[k][n'&1023], n' in [0,3072), fp16 hi+lo
__global__ void wsplit_kernel(const float* __restrict__ Wq, const float* __restrict__ Wk,
                              const float* __restrict__ Wv, f16* __restrict__ wt_hi,
                              f16* __restrict__ wt_lo) {
  __shared__ float tile[32][33];
  const int k0 = blockIdx.x * 32;
  const int n0g = blockIdx.y * 32;
  const int which = n0g >> 10;
  const float* W = which == 0 ? Wq : (which == 1 ? Wk : Wv);
  const int n0 = n0g & 1023;
  const int tx = threadIdx.x, ty = threadIdx.y;
#pragma unroll
  for (int i = 0; i < 32; i += 8)
    tile[ty + i][tx] = W[(size_t)(k0 + ty + i) * 1024 + n0 + tx];
  __syncthreads();
#pragma unroll
  for (int i = 0; i < 32; i += 8) {
    const int np = n0g + ty + i;
    const float v = tile[tx][ty + i];
    const size_t idx = (size_t)np * 1024 + k0 + tx;
    const f16 h = (f16)v;
    wt_hi[idx] = h;
    wt_lo[idx] = (f16)(v - (float)h);
  }
}

// ---------------------------------------------------------------------------
// Projection GEMM: rows = [8192 token rows | 2048 ext rows], cols = [q|k|v]
// q/k col-tiles (ntile<16): 2-term split. v col-tiles: plain. Ext skips q.
// ---------------------------------------------------------------------------
__global__ __launch_bounds__(256, 4) void proj_kernel(
    const f16* __restrict__ xh, const f16* __restrict__ xe,
    const f16* __restrict__ wt_hi, const f16* __restrict__ wt_lo,
    const float* __restrict__ bq, const float* __restrict__ bk,
    const float* __restrict__ bv, f16* __restrict__ q_hi, f16* __restrict__ q_lo,
    f16* __restrict__ kt_hi, f16* __restrict__ kt_lo, f16* __restrict__ vt,
    f16* __restrict__ ke_hi, f16* __restrict__ ke_lo, f16* __restrict__ veT) {
  const int ntile = blockIdx.x;  // 0..23 (3072 cols)
  const int mtile = blockIdx.y;  // 0..79 (10240 rows)
  const bool extRows = (mtile >= 64);
  if (extRows && ntile < 8) return;  // ext rows need no q

  __shared__ f16 lds[3][128 * 32];

  const f16* A;
  int rowA;
  if (!extRows) { A = xh; rowA = mtile * 128; }
  else          { A = xe; rowA = (mtile - 64) * 128; }
  const int rowB = ntile * 128;

  f32x4 acc[4][4];
#pragma unroll
  for (int i = 0; i < 4; ++i)
#pragma unroll
    for (int j = 0; j < 4; ++j)
#pragma unroll
      for (int r = 0; r < 4; ++r) acc[i][j][r] = 0.0f;

  if (ntile < 16)
    gemm_core<true>(A + (size_t)rowA * HH, wt_hi + (size_t)rowB * HH,
                    wt_lo + (size_t)rowB * HH, HH, HH, lds[0], lds[1], lds[2], acc);
  else
    gemm_core<false>(A + (size_t)rowA * HH, wt_hi + (size_t)rowB * HH, nullptr,
                     HH, HH, lds[0], lds[1], nullptr, acc);

  const int tid = threadIdx.x, wave = tid >> 6, lane = tid & 63;
  const int waveM = (wave >> 1) * 64, waveN = (wave & 1) * 64;
  const int colIn16 = lane & 15, rowQuad = (lane >> 4) * 4;

#pragma unroll
  for (int j = 0; j < 4; ++j) {
    const int c = ntile * 128 + waveN + j * 16 + colIn16;  // 0..3071
    float bias;
    if (c < 1024) bias = bq[c];
    else if (c < 2048) bias = bk[c - 1024];
    else bias = bv[c - 2048];
#pragma unroll
    for (int i = 0; i < 4; ++i) {
#pragma unroll
      for (int r = 0; r < 4; ++r) {
        const int lrowIdx = waveM + i * 16 + rowQuad + r;  // 0..127
        const float val = acc[i][j][r] + bias;
        if (c < 1024) {  // q (token rows only)
          const size_t idx = (size_t)(mtile * 128 + lrowIdx) * HH + c;
          const f16 h = (f16)val;
          q_hi[idx] = h;
          q_lo[idx] = (f16)(val - (float)h);
        } else if (c < 2048) {  // k
          const int c2 = c - 1024;
          if (!extRows) {
            const size_t idx = (size_t)(mtile * 128 + lrowIdx) * HH + c2;
            const f16 h = (f16)val;
            kt_hi[idx] = h;
            kt_lo[idx] = (f16)(val - (float)h);
          } else {
            const int ge = (mtile - 64) * 128 + lrowIdx;
            const size_t idx = (size_t)ge * HH + c2;
            const f16 h = (f16)val;
            ke_hi[idx] = h;
            ke_lo[idx] = (f16)(val - (float)h);
          }
        } else {  // v
          const int c2 = c - 2048;
          if (!extRows) {
            vt[(size_t)(mtile * 128 + lrowIdx) * HH + c2] = (f16)val;
          } else {
            const int ge = (mtile - 64) * 128 + lrowIdx;  // 0..2047
            const int bb = ge >> 9, e = ge & 511;
            veT[(size_t)(bb * HH + c2) * EE + e] = (f16)val;  // [B][H][E]
          }
        }
      }
    }
  }
}

// Score GEMM, split-K: s_part[khalf][b][s][e] = q[b,s,kh*512:+512] . k_ext[...]
// A = q_hi (2-term: B=ke hi+lo). Grid (4,16,8): z&3 = b, z>>2 = khalf.
__global__ __launch_bounds__(256, 4) void score_kernel(
    const f16* __restrict__ q_hi, const f16* __restrict__ ke_hi,
    const f16* __restrict__ ke_lo, float* __restrict__ s_part) {
  const int b = blockIdx.z & 3;
  const int khalf = blockIdx.z >> 2;
  const int mtile = blockIdx.y;  // 0..15
  const int ntile = blockIdx.x;  // 0..3
  __shared__ f16 lds[3][128 * 32];
  const size_t aoff = ((size_t)b * SS + mtile * 128) * HH + khalf * 512;
  const size_t boff = ((size_t)b * EE + ntile * 128) * HH + khalf * 512;

  f32x4 acc[4][4];
#pragma unroll
  for (int i = 0; i < 4; ++i)
#pragma unroll
    for (int j = 0; j < 4; ++j)
#pragma unroll
      for (int r = 0; r < 4; ++r) acc[i][j][r] = 0.0f;

  gemm_core<true>(q_hi + aoff, ke_hi + boff, ke_lo + boff, 512, HH,
                  lds[0], lds[1], lds[2], acc);

  float* dst = s_part + (size_t)khalf * BB * SS * EE;
  const int tid = threadIdx.x, wave = tid >> 6, lane = tid & 63;
  const int waveM = (wave >> 1) * 64, waveN = (wave & 1) * 64;
  const int colIn16 = lane & 15, rowQuad = (lane >> 4) * 4;
#pragma unroll
  for (int j = 0; j < 4; ++j) {
    const int e = ntile * 128 + waveN + j * 16 + colIn16;
#pragma unroll
    for (int i = 0; i < 4; ++i)
#pragma unroll
      for (int r = 0; r < 4; ++r) {
        const int s = mtile * 128 + waveM + i * 16 + rowQuad + r;
        dst[((size_t)b * SS + s) * EE + e] = acc[i][j][r];
      }
  }
}

// Fused selfdot + softmax: per token, s_self = q.k_tok (fp32 from hi+lo),
// softmax over [s_self, s_part0+s_part1]; probs -> fp16, p_self -> fp32.
__global__ __launch_bounds__(256) void softmax_kernel(
    const f16* __restrict__ q_hi, const f16* __restrict__ q_lo,
    const f16* __restrict__ kt_hi, const f16* __restrict__ kt_lo,
    const float* __restrict__ s_part, f16* __restrict__ probs,
    float* __restrict__ p_self) {
  const int t = blockIdx.x * 4 + (threadIdx.x >> 6);
  const int lane = threadIdx.x & 63;

  // selfdot
  const size_t base = (size_t)t * HH;
  float ss = 0.f;
#pragma unroll
  for (int it = 0; it < 4; ++it) {
    const int off = it * 256 + lane * 4;
    const f16x4 qh = *(const f16x4*)&q_hi[base + off];
    const f16x4 ql = *(const f16x4*)&q_lo[base + off];
    const f16x4 kh = *(const f16x4*)&kt_hi[base + off];
    const f16x4 kl = *(const f16x4*)&kt_lo[base + off];
    ss += ((float)qh.x + (float)ql.x) * ((float)kh.x + (float)kl.x);
    ss += ((float)qh.y + (float)ql.y) * ((float)kh.y + (float)kl.y);
    ss += ((float)qh.z + (float)ql.z) * ((float)kh.z + (float)kl.z);
    ss += ((float)qh.w + (float)ql.w) * ((float)kh.w + (float)kl.w);
  }
#pragma unroll
  for (int m = 32; m > 0; m >>= 1) ss += __shfl_xor(ss, m, 64);

  // softmax over 1 + 512
  const float* r0 = s_part + (size_t)t * EE;
  const float* r1 = s_part + (size_t)BB * SS * EE + (size_t)t * EE;
  const float4 a0 = *(const float4*)&r0[lane * 4];
  const float4 a1 = *(const float4*)&r0[256 + lane * 4];
  const float4 c0 = *(const float4*)&r1[lane * 4];
  const float4 c1 = *(const float4*)&r1[256 + lane * 4];
  const float v0x = a0.x + c0.x, v0y = a0.y + c0.y, v0z = a0.z + c0.z, v0w = a0.w + c0.w;
  const float v1x = a1.x + c1.x, v1y = a1.y + c1.y, v1z = a1.z + c1.z, v1w = a1.w + c1.w;
  float m = fmaxf(fmaxf(fmaxf(v0x, v0y), fmaxf(v0z, v0w)),
                  fmaxf(fmaxf(v1x, v1y), fmaxf(v1z, v1w)));
#pragma unroll
  for (int sh = 32; sh > 0; sh >>= 1) m = fmaxf(m, __shfl_xor(m, sh, 64));
  m = fmaxf(m, ss);
  const float e0 = __expf(v0x - m), e1 = __expf(v0y - m);
  const float e2 = __expf(v0z - m), e3 = __expf(v0w - m);
  const float e4 = __expf(v1x - m), e5 = __expf(v1y - m);
  const float e6 = __expf(v1z - m), e7 = __expf(v1w - m);
  float sum = ((e0 + e1) + (e2 + e3)) + ((e4 + e5) + (e6 + e7));
#pragma unroll
  for (int sh = 32; sh > 0; sh >>= 1) sum += __shfl_xor(sum, sh, 64);
  const float es = __expf(ss - m);
  const float inv = 1.0f / (sum + es);
  f16x4 p0, p1;
  p0.x = (f16)(e0 * inv); p0.y = (f16)(e1 * inv);
  p0.z = (f16)(e2 * inv); p0.w = (f16)(e3 * inv);
  p1.x = (f16)(e4 * inv); p1.y = (f16)(e5 * inv);
  p1.z = (f16)(e6 * inv); p1.w = (f16)(e7 * inv);
  *(f16x4*)&probs[(size_t)t * EE + lane * 4] = p0;
  *(f16x4*)&probs[(size_t)t * EE + 256 + lane * 4] = p1;
  if (lane == 0) p_self[t] = es * inv;
}

// PV GEMM per batch: out[b,s,h] = probs[b,s,:] . v_ext[b,:,h] + p_self*v_tok
__global__ __launch_bounds__(256, 4) void pv_kernel(
    const f16* __restrict__ probs, const f16* __restrict__ veT,
    const float* __restrict__ p_self, const f16* __restrict__ vt,
    float* __restrict__ out) {
  const int b = blockIdx.z;
  const int mtile = blockIdx.y;  // 0..15 (S)
  const int ntile = blockIdx.x;  // 0..7  (H)
  __shared__ f16 lds[2][128 * 32];
  const size_t aoff = ((size_t)b * SS + mtile * 128) * EE;
  const size_t boff = ((size_t)b * HH + ntile * 128) * EE;

  f32x4 acc[4][4];
#pragma unroll
  for (int i = 0; i < 4; ++i)
#pragma unroll
    for (int j = 0; j < 4; ++j)
#pragma unroll
      for (int r = 0; r < 4; ++r) acc[i][j][r] = 0.0f;

  gemm_core<false>(probs + aoff, veT + boff, nullptr, EE, EE,
                   lds[0], lds[1], nullptr, acc);

  const int tid = threadIdx.x, wave = tid >> 6, lane = tid & 63;
  const int waveM = (wave >> 1) * 64, waveN = (wave & 1) * 64;
  const int colIn16 = lane & 15, rowQuad = (lane >> 4) * 4;
#pragma unroll
  for (int j = 0; j < 4; ++j) {
    const int h = ntile * 128 + waveN + j * 16 + colIn16;
#pragma unroll
    for (int i = 0; i < 4; ++i)
#pragma unroll
      for (int r = 0; r < 4; ++r) {
        const int s = mtile * 128 + waveM + i * 16 + rowQuad + r;
        const size_t t = (size_t)b * SS + s;
        out[t * HH + h] = acc[i][j][r] + p_self[t] * (float)vt[t * HH + h];
      }
  }
}

extern "C" void kernel_launch(void* const* d_in, const int* in_sizes, int n_in,
                              void* d_out, int out_size, void* d_ws, size_t ws_size,
                              hipStream_t stream) {
  const float* hidden = (const float*)d_in[0];
  const float* ext    = (const float*)d_in[1];
  const float* Wq = (const float*)d_in[2];
  const float* bq = (const float*)d_in[3];
  const float* Wk = (const float*)d_in[4];
  const float* bk = (const float*)d_in[5];
  const float* Wv = (const float*)d_in[6];
  const float* bv = (const float*)d_in[7];
  float* out = (float*)d_out;

  char* ws = (char*)d_ws;
  size_t off = 0;
  auto alloc = [&](size_t bytes) {
    char* p = ws + off;
    off += (bytes + 255) & ~(size_t)255;
    return p;
  };
  const size_t TOK = 8192, EXT = 2048;
  f16* xh    = (f16*)alloc(TOK * HH * 2);
  f16* xe    = (f16*)alloc(EXT * HH * 2);
  f16* wt_hi = (f16*)alloc(3072ull * HH * 2);
  f16* wt_lo = (f16*)alloc(3072ull * HH * 2);
  f16* q_hi  = (f16*)alloc(TOK * HH * 2);
  f16* q_lo  = (f16*)alloc(TOK * HH * 2);
  f16* kt_hi = (f16*)alloc(TOK * HH * 2);
  f16* kt_lo = (f16*)alloc(TOK * HH * 2);
  f16* vt    = (f16*)alloc(TOK * HH * 2);
  f16* ke_hi = (f16*)alloc(EXT * HH * 2);
  f16* ke_lo = (f16*)alloc(EXT * HH * 2);
  f16* veT   = (f16*)alloc((size_t)BB * HH * EE * 2);
  float* p_self = (float*)alloc(TOK * 4);
  float* s_part = (float*)alloc(2ull * BB * SS * EE * 4);
  f16* probs    = (f16*)alloc((size_t)BB * SS * EE * 2);

  // 1. cast A-side inputs to fp16; transpose+split W to fp16 hi/lo
  cast_kernel<<<8192, 256, 0, stream>>>(hidden, xh, (int)(TOK * HH / 4));
  cast_kernel<<<2048, 256, 0, stream>>>(ext, xe, (int)(EXT * HH / 4));
  wsplit_kernel<<<dim3(32, 96), dim3(32, 8), 0, stream>>>(Wq, Wk, Wv, wt_hi, wt_lo);

  // 2. fused projection GEMM (q,k 2-term split; v plain)
  proj_kernel<<<dim3(24, 80), 256, 0, stream>>>(
      xh, xe, wt_hi, wt_lo, bq, bk, bv,
      q_hi, q_lo, kt_hi, kt_lo, vt, ke_hi, ke_lo, veT);

  // 3. attention
  score_kernel<<<dim3(4, 16, 8), 256, 0, stream>>>(q_hi, ke_hi, ke_lo, s_part);
  softmax_kernel<<<2048, 256, 0, stream>>>(q_hi, q_lo, kt_hi, kt_lo, s_part, probs, p_self);
  pv_kernel<<<dim3(8, 16, 4), 256, 0, stream>>>(probs, veT, p_self, vt, out);
}